// Round 6
// baseline (269.076 us; speedup 1.0000x reference)
//
#include <hip/hip_runtime.h>
#include <math.h>

#define N_    4096
#define NPAIR (N_ * 7)   // 28672

typedef unsigned short u16;
typedef __attribute__((ext_vector_type(8))) short bf16x8;
typedef __attribute__((ext_vector_type(4))) float f32x4;

__device__ __forceinline__ float sigm(float x) { return 1.0f / (1.0f + __expf(-x)); }
__device__ __forceinline__ float tanh_fast(float x) { return 2.0f / (1.0f + __expf(-2.0f * x)) - 1.0f; }
__device__ __forceinline__ float bf2f(u16 u) { return __uint_as_float(((unsigned)u) << 16); }
__device__ __forceinline__ u16 f2bf(float f) {
  unsigned u = __float_as_uint(f);
  return (u16)((u + 0x7FFFu + ((u >> 16) & 1u)) >> 16);
}
__device__ __forceinline__ f32x4 mfma16(bf16x8 a, bf16x8 b, f32x4 c) {
  return __builtin_amdgcn_mfma_f32_16x16x32_bf16(a, b, c, 0, 0, 0);
}

// ---------------- k_prep_all: all weight fp32->bf16 conversions, one launch --------
__global__ __launch_bounds__(256) void k_prep_all(
    const float* __restrict__ msg_W, const float* __restrict__ lin_W,
    const float* __restrict__ g0_Wih, const float* __restrict__ g1_Wih,
    const float* __restrict__ c_Wih, const float* __restrict__ lin2_W,
    const float* __restrict__ g0_Whh, const float* __restrict__ g1_Whh,
    const float* __restrict__ c_Whh, const float* __restrict__ hyp_W,
    u16* __restrict__ wbase)
{
  const int task = blockIdx.y;
  const int i = blockIdx.x * 256 + threadIdx.x;
  int R, KD, stride, koff, doff;
  const float* src;
  switch (task) {
    case 0:  R=128; KD=256; stride=256; koff=0;   src=msg_W;  doff=0;      break;
    case 1:  R=128; KD=256; stride=256; koff=0;   src=lin_W;  doff=32768;  break;
    case 2:  R=384; KD=128; stride=128; koff=0;   src=g0_Wih; doff=65536;  break;
    case 3:  R=384; KD=128; stride=128; koff=0;   src=g1_Wih; doff=114688; break;
    case 4:  R=384; KD=128; stride=128; koff=0;   src=c_Wih;  doff=163840; break;
    case 5:  R=128; KD=128; stride=256; koff=128; src=lin2_W; doff=212992; break;  // l2w = lin2_W[:,128:]
    case 6:  R=128; KD=128; stride=256; koff=0;   src=lin2_W; doff=229376; break;  // w2a = lin2_W[:,:128]
    case 7:  R=384; KD=128; stride=128; koff=0;   src=g0_Whh; doff=245760; break;
    case 8:  R=384; KD=128; stride=128; koff=0;   src=g1_Whh; doff=294912; break;
    case 9:  R=384; KD=128; stride=128; koff=0;   src=c_Whh;  doff=344064; break;
    default: R=128; KD=128; stride=128; koff=0;   src=hyp_W;  doff=393216; break;
  }
  if (i >= R * KD) return;
  const int r = i / KD, k = i - r * KD;
  wbase[doff + i] = f2bf(src[(size_t)r * stride + koff + k]);
}

// ---------------- k1_fused: sequential X stream + weighted reduce + msg/lin MFMA ----
// ONE block per n. Wave v streams m in [1+8v, 8+8v] (contiguous 56KB run).
// acc[7] (per-w) in registers; 4-wave LDS reduce; 7-valid-row MFMA tile.
__global__ __launch_bounds__(256) void k1_fused(
    const float* __restrict__ X, const float* __restrict__ C,
    const u16* __restrict__ msgw, const u16* __restrict__ linw,   // [128][256] bf16
    const float* __restrict__ msg_b, const float* __restrict__ lin_b,
    u16* __restrict__ hmsg, u16* __restrict__ hself)
{
  __shared__ float s_part[4][7][260];
  __shared__ u16 sXW[16 * 256];
  __shared__ u16 sTX[16 * 256];
  __shared__ float s_c[224];
  __shared__ float s_ps[8];
  const int tid = threadIdx.x, lane = tid & 63, wave = tid >> 6;
  const int n = blockIdx.x;
  const size_t slab = (size_t)n * 59136;   // n*33*7*256

  // zero both MFMA tiles (pad rows must be 0)
  {
    uint4 z = {0, 0, 0, 0};
    *(uint4*)&sXW[tid * 8] = z;
    *(uint4*)&sXW[2048 + tid * 8] = z;
    *(uint4*)&sTX[tid * 8] = z;
    *(uint4*)&sTX[2048 + tid * 8] = z;
  }
  if (tid < 224) s_c[tid] = C[(size_t)n * 231 + 7 + tid];
  __syncthreads();

  if (tid < 7) {
    float s = 0.f;
    #pragma unroll 8
    for (int j = 0; j < 32; ++j) s += s_c[j * 7 + tid];
    s_ps[tid] = s;
  }

  // ---- sequential weighted stream: wave owns m in [1+8*wave, 8+8*wave] ----
  float4 acc[7];
  #pragma unroll
  for (int w = 0; w < 7; ++w) acc[w] = make_float4(0.f, 0.f, 0.f, 0.f);
  {
    const float* xr0 = X + slab + (size_t)(1 + wave * 8) * 1792 + lane * 4;
    #pragma unroll 2
    for (int mi = 0; mi < 8; ++mi) {
      const int m = wave * 8 + mi;   // s_c index uses m (= real_m - 1)
      const float* xr = xr0 + (size_t)mi * 1792;
      #pragma unroll
      for (int w = 0; w < 7; ++w) {
        const float c = s_c[m * 7 + w];
        const float4 x4 = *(const float4*)(xr + w * 256);
        acc[w].x += c * x4.x; acc[w].y += c * x4.y;
        acc[w].z += c * x4.z; acc[w].w += c * x4.w;
      }
    }
  }
  #pragma unroll
  for (int w = 0; w < 7; ++w)
    *(float4*)&s_part[wave][w][lane * 4] = acc[w];

  // ---- target rows -> sTX (sequential 7KB) ----
  #pragma unroll
  for (int it = 0; it < 7; ++it) {
    const int i = it * 256 + tid;
    const int w = i >> 8, f = i & 255;
    const float v = X[slab + (size_t)w * 256 + f];
    *(u16*)((char*)sTX + w * 512 + ((f * 2) ^ ((w & 7) << 4))) = f2bf(v);
  }
  __syncthreads();

  // ---- 4-wave reduce -> sXW ----
  #pragma unroll
  for (int w = 0; w < 7; ++w) {
    const float v = s_part[0][w][tid] + s_part[1][w][tid] +
                    s_part[2][w][tid] + s_part[3][w][tid];
    *(u16*)((char*)sXW + w * 512 + ((tid * 2) ^ ((w & 7) << 4))) = f2bf(v);
  }
  __syncthreads();

  // ---- MFMA epilogue: [7(pad16) x 256] @ W^T for msg and lin ----
  const int l15 = lane & 15, lq = lane >> 4;
  bf16x8 ax[8], at[8];
  #pragma unroll
  for (int kc = 0; kc < 8; ++kc) {
    const int off = l15 * 512 + ((lq * 16 + kc * 64) ^ ((l15 & 7) << 4));
    ax[kc] = *(const bf16x8*)((const char*)sXW + off);
    at[kc] = *(const bf16x8*)((const char*)sTX + off);
  }
  #pragma unroll
  for (int ct = 0; ct < 2; ++ct) {
    const int col = (wave + ct * 4) * 16 + l15;
    f32x4 am = {0.f, 0.f, 0.f, 0.f}, as = {0.f, 0.f, 0.f, 0.f};
    #pragma unroll
    for (int kc = 0; kc < 8; ++kc) {
      const bf16x8 bm = *(const bf16x8*)(msgw + (size_t)col * 256 + lq * 8 + kc * 32);
      const bf16x8 bl = *(const bf16x8*)(linw + (size_t)col * 256 + lq * 8 + kc * 32);
      am = mfma16(ax[kc], bm, am);
      as = mfma16(at[kc], bl, as);
    }
    const float mb = msg_b[col], lb = lin_b[col];
    #pragma unroll
    for (int r = 0; r < 4; ++r) {
      const int row = lq * 4 + r;
      if (row < 7) {
        const int p = n * 7 + row;
        hmsg[(size_t)p * 128 + col]  = f2bf(am[r] + mb * s_ps[row]);
        hself[(size_t)p * 128 + col] = f2bf(as[r] + lb);
      }
    }
  }
}

// ---------------- k_chain: gru0 -> gru1 -> (lin2+cell) -> head, 16 n / block --------
__device__ __forceinline__ void stage16(u16* __restrict__ dst,
                                        const u16* __restrict__ src,
                                        int n0, int tid)
{
  #pragma unroll
  for (int it = 0; it < 7; ++it) {
    const int chunk = it * 256 + tid;
    const int w = chunk >> 8, rem = chunk & 255;
    const int n = rem >> 4, d0 = (rem & 15) * 8;
    const uint4 v = *(const uint4*)(src + ((size_t)(n0 + n) * 7 + w) * 128 + d0);
    *(uint4*)((char*)dst + w * 4096 + n * 256 + ((d0 * 2) ^ ((n & 7) << 4))) = v;
  }
}

__device__ __forceinline__ void gru_stage(
    u16* __restrict__ sin, u16* __restrict__ sout,
    const u16* __restrict__ wih, const u16* __restrict__ whh,
    const float* __restrict__ bih, const float* __restrict__ bhh,
    int wave, int l15, int lq)
{
  bf16x8 wi[6][4], wh[6][4];
  float binit[6], bxn[2];
  #pragma unroll
  for (int i = 0; i < 6; ++i) {
    const int g = (wave + i * 4) * 16 + l15;
    #pragma unroll
    for (int kc = 0; kc < 4; ++kc) {
      wi[i][kc] = *(const bf16x8*)(wih + (size_t)g * 128 + lq * 8 + kc * 32);
      wh[i][kc] = *(const bf16x8*)(whh + (size_t)g * 128 + lq * 8 + kc * 32);
    }
    binit[i] = (i < 4) ? (bih[g] + bhh[g]) : bhh[g];
    if (i >= 4) bxn[i - 4] = bih[g];
  }
  float hold[2][4] = {{0.f, 0.f, 0.f, 0.f}, {0.f, 0.f, 0.f, 0.f}};

  for (int w = 0; w < 7; ++w) {
    bf16x8 afx[4], afh[4];
    #pragma unroll
    for (int kc = 0; kc < 4; ++kc) {
      const int off = l15 * 256 + ((lq * 16 + kc * 64) ^ ((l15 & 7) << 4));
      afx[kc] = *(const bf16x8*)((const char*)sin + w * 4096 + off);
      if (w) afh[kc] = *(const bf16x8*)((const char*)sout + (w - 1) * 4096 + off);
    }
    f32x4 acc[6], accx[2];
    #pragma unroll
    for (int i = 0; i < 6; ++i) acc[i] = (f32x4){binit[i], binit[i], binit[i], binit[i]};
    #pragma unroll
    for (int t = 0; t < 2; ++t) accx[t] = (f32x4){bxn[t], bxn[t], bxn[t], bxn[t]};

    #pragma unroll
    for (int i = 0; i < 6; ++i) {
      #pragma unroll
      for (int kc = 0; kc < 4; ++kc) {
        if (i < 4) acc[i] = mfma16(afx[kc], wi[i][kc], acc[i]);
        else       accx[i - 4] = mfma16(afx[kc], wi[i][kc], accx[i - 4]);
        if (w) acc[i] = mfma16(afh[kc], wh[i][kc], acc[i]);
      }
    }
    #pragma unroll
    for (int t = 0; t < 2; ++t) {
      const int d = (wave + t * 4) * 16 + l15;
      #pragma unroll
      for (int r = 0; r < 4; ++r) {
        const float rg = sigm(acc[t][r]);
        const float zg = sigm(acc[t + 2][r]);
        const float nn = tanh_fast(accx[t][r] + rg * acc[t + 4][r]);
        const float hv = (1.f - zg) * nn + zg * hold[t][r];
        hold[t][r] = hv;
        const int n = lq * 4 + r;
        *(u16*)((char*)sout + w * 4096 + n * 256 + ((d * 2) ^ ((n & 7) << 4))) = f2bf(hv);
      }
    }
    __syncthreads();
  }
}

__global__ __launch_bounds__(256, 1) void k_chain(
    const u16* __restrict__ hmsg, const u16* __restrict__ hself,
    const u16* __restrict__ wbase,
    const float* __restrict__ g0_bih, const float* __restrict__ g0_bhh,
    const float* __restrict__ g1_bih, const float* __restrict__ g1_bhh,
    const float* __restrict__ lin2_b,
    const float* __restrict__ c_bih, const float* __restrict__ c_bhh,
    const float* __restrict__ hyp_b,
    const float* __restrict__ bn_g, const float* __restrict__ bn_be,
    const float* __restrict__ bn_m, const float* __restrict__ bn_v,
    const float* __restrict__ out_W, const float* __restrict__ out_b,
    const float* __restrict__ Y,
    float* __restrict__ outp, float* __restrict__ bloss)
{
  __shared__ u16 sA[7 * 2048];   // 28 KB
  __shared__ u16 sB[7 * 2048];   // 28 KB
  __shared__ u16 sC[2048];       // 4 KB
  __shared__ u16 sD[2048];       // 4 KB
  __shared__ float s_red[16][66];
  __shared__ float s_ls[16];

  const int tid = threadIdx.x;
  const int lane = tid & 63, wave = tid >> 6;
  const int l15 = lane & 15, lq = lane >> 4;
  const int n0 = blockIdx.x * 16;

  const u16* g0wih = wbase + 65536;
  const u16* g1wih = wbase + 114688;
  const u16* cwih  = wbase + 163840;
  const u16* l2w   = wbase + 212992;
  const u16* w2a   = wbase + 229376;
  const u16* whh0  = wbase + 245760;
  const u16* whh1  = wbase + 294912;
  const u16* whhc  = wbase + 344064;
  const u16* hypw  = wbase + 393216;

  stage16(sA, hmsg, n0, tid);
  __syncthreads();

  gru_stage(sA, sB, g0wih, whh0, g0_bih, g0_bhh, wave, l15, lq);  // h0 -> sB
  gru_stage(sB, sA, g1wih, whh1, g1_bih, g1_bhh, wave, l15, lq);  // h1 -> sA

  stage16(sB, hself, n0, tid);   // h0 dead; sB <- hself
  __syncthreads();

  // ---- cell chain: hx1 = tanh(w2a@hx + l2w@h1 + b2); hx = GRU_c(Wc@hself, hx1) ----
  {
    bf16x8 lw[2][4], wa[2][4], wi[6][4], wh[6][4];
    float b2[2], cbin[6], cbxn[2];
    #pragma unroll
    for (int t = 0; t < 2; ++t) {
      const int d = (wave + t * 4) * 16 + l15;
      #pragma unroll
      for (int kc = 0; kc < 4; ++kc) {
        lw[t][kc] = *(const bf16x8*)(l2w + (size_t)d * 128 + lq * 8 + kc * 32);
        wa[t][kc] = *(const bf16x8*)(w2a + (size_t)d * 128 + lq * 8 + kc * 32);
      }
      b2[t] = lin2_b[d];
    }
    #pragma unroll
    for (int i = 0; i < 6; ++i) {
      const int g = (wave + i * 4) * 16 + l15;
      #pragma unroll
      for (int kc = 0; kc < 4; ++kc) {
        wi[i][kc] = *(const bf16x8*)(cwih + (size_t)g * 128 + lq * 8 + kc * 32);
        wh[i][kc] = *(const bf16x8*)(whhc + (size_t)g * 128 + lq * 8 + kc * 32);
      }
      cbin[i] = (i < 4) ? (c_bih[g] + c_bhh[g]) : c_bhh[g];
      if (i >= 4) cbxn[i - 4] = c_bih[g];
    }

    for (int w = 0; w < 7; ++w) {
      // round 1: hx1
      bf16x8 af1[4], afx_[4];
      #pragma unroll
      for (int kc = 0; kc < 4; ++kc) {
        const int off = l15 * 256 + ((lq * 16 + kc * 64) ^ ((l15 & 7) << 4));
        af1[kc] = *(const bf16x8*)((const char*)sA + w * 4096 + off);
        if (w) afx_[kc] = *(const bf16x8*)((const char*)sD + off);
      }
      f32x4 a1[2];
      #pragma unroll
      for (int t = 0; t < 2; ++t) a1[t] = (f32x4){b2[t], b2[t], b2[t], b2[t]};
      #pragma unroll
      for (int t = 0; t < 2; ++t)
        #pragma unroll
        for (int kc = 0; kc < 4; ++kc) {
          a1[t] = mfma16(af1[kc], lw[t][kc], a1[t]);
          if (w) a1[t] = mfma16(afx_[kc], wa[t][kc], a1[t]);
        }
      float hx1[2][4];
      #pragma unroll
      for (int t = 0; t < 2; ++t) {
        const int d = (wave + t * 4) * 16 + l15;
        #pragma unroll
        for (int r = 0; r < 4; ++r) {
          hx1[t][r] = tanh_fast(a1[t][r]);
          const int n = lq * 4 + r;
          *(u16*)((char*)sC + n * 256 + ((d * 2) ^ ((n & 7) << 4))) = f2bf(hx1[t][r]);
        }
      }
      __syncthreads();

      // round 2: cell GRU
      bf16x8 afs[4], aft[4];
      #pragma unroll
      for (int kc = 0; kc < 4; ++kc) {
        const int off = l15 * 256 + ((lq * 16 + kc * 64) ^ ((l15 & 7) << 4));
        afs[kc] = *(const bf16x8*)((const char*)sB + w * 4096 + off);
        aft[kc] = *(const bf16x8*)((const char*)sC + off);
      }
      f32x4 acc[6], accx[2];
      #pragma unroll
      for (int i = 0; i < 6; ++i) acc[i] = (f32x4){cbin[i], cbin[i], cbin[i], cbin[i]};
      #pragma unroll
      for (int t = 0; t < 2; ++t) accx[t] = (f32x4){cbxn[t], cbxn[t], cbxn[t], cbxn[t]};
      #pragma unroll
      for (int i = 0; i < 6; ++i)
        #pragma unroll
        for (int kc = 0; kc < 4; ++kc) {
          if (i < 4) acc[i] = mfma16(afs[kc], wi[i][kc], acc[i]);
          else       accx[i - 4] = mfma16(afs[kc], wi[i][kc], accx[i - 4]);
          acc[i] = mfma16(aft[kc], wh[i][kc], acc[i]);
        }
      #pragma unroll
      for (int t = 0; t < 2; ++t) {
        const int d = (wave + t * 4) * 16 + l15;
        #pragma unroll
        for (int r = 0; r < 4; ++r) {
          const float rg = sigm(acc[t][r]);
          const float zg = sigm(acc[t + 2][r]);
          const float nn = tanh_fast(accx[t][r] + rg * acc[t + 4][r]);
          const float hv = (1.f - zg) * nn + zg * hx1[t][r];
          const int n = lq * 4 + r;
          *(u16*)((char*)sD + n * 256 + ((d * 2) ^ ((n & 7) << 4))) = f2bf(hv);
        }
      }
      __syncthreads();
    }
  }

  // ---- head: relu(BN(hyp_W@hx + hyp_b)) -> y -> sigmoid + loss partial ----
  {
    bf16x8 af[4];
    #pragma unroll
    for (int kc = 0; kc < 4; ++kc) {
      const int off = l15 * 256 + ((lq * 16 + kc * 64) ^ ((l15 & 7) << 4));
      af[kc] = *(const bf16x8*)((const char*)sD + off);
    }
    f32x4 ah[2];
    float sc[2], mu[2], be[2], ow[2];
    #pragma unroll
    for (int t = 0; t < 2; ++t) {
      const int q = (wave + t * 4) * 16 + l15;
      const float hb = hyp_b[q];
      ah[t] = (f32x4){hb, hb, hb, hb};
      sc[t] = rsqrtf(bn_v[q] + 1e-5f) * bn_g[q];
      mu[t] = bn_m[q]; be[t] = bn_be[q]; ow[t] = out_W[q];
      #pragma unroll
      for (int kc = 0; kc < 4; ++kc) {
        const bf16x8 hf = *(const bf16x8*)(hypw + (size_t)q * 128 + lq * 8 + kc * 32);
        ah[t] = mfma16(af[kc], hf, ah[t]);
      }
    }
    float part[4] = {0.f, 0.f, 0.f, 0.f};
    #pragma unroll
    for (int t = 0; t < 2; ++t)
      #pragma unroll
      for (int r = 0; r < 4; ++r) {
        const float v = (ah[t][r] - mu[t]) * sc[t] + be[t];
        part[r] += ow[t] * fmaxf(v, 0.f);
      }
    #pragma unroll
    for (int r = 0; r < 4; ++r) s_red[lq * 4 + r][wave * 16 + l15] = part[r];
  }
  __syncthreads();
  if (tid < 16) {
    const int n = tid;
    float y = out_b[0];
    #pragma unroll 8
    for (int c = 0; c < 64; ++c) y += s_red[n][c];
    outp[1 + n0 + n] = 1.f / (1.f + __expf(-y));
    const float tY = Y[(size_t)(n0 + n) * 33];
    s_ls[n] = fmaxf(y, 0.f) - y * tY + log1pf(__expf(-fabsf(y)));
  }
  __syncthreads();
  if (tid == 0) {
    float s = 0.f;
    #pragma unroll
    for (int j = 0; j < 16; ++j) s += s_ls[j];
    bloss[blockIdx.x] = s;
  }
}

// ---------------- K3: loss reduction (256 partials) ----------------
__global__ __launch_bounds__(256) void k3_loss(const float* __restrict__ bloss,
                                               float* __restrict__ out)
{
  __shared__ float s[256];
  s[threadIdx.x] = bloss[threadIdx.x];
  __syncthreads();
  for (int off = 128; off > 0; off >>= 1) {
    if (threadIdx.x < off) s[threadIdx.x] += s[threadIdx.x + off];
    __syncthreads();
  }
  if (threadIdx.x == 0) out[0] = s[0] * (1.0f / 4096.0f);
}

extern "C" void kernel_launch(void* const* d_in, const int* in_sizes, int n_in,
                              void* d_out, int out_size, void* d_ws, size_t ws_size,
                              hipStream_t stream) {
  const float* X       = (const float*)d_in[0];
  const float* Y       = (const float*)d_in[1];
  const float* C       = (const float*)d_in[2];
  const float* msg_W   = (const float*)d_in[3];
  const float* msg_b   = (const float*)d_in[4];
  const float* g0_Wih  = (const float*)d_in[5];
  const float* g0_Whh  = (const float*)d_in[6];
  const float* g0_bih  = (const float*)d_in[7];
  const float* g0_bhh  = (const float*)d_in[8];
  const float* g1_Wih  = (const float*)d_in[9];
  const float* g1_Whh  = (const float*)d_in[10];
  const float* g1_bih  = (const float*)d_in[11];
  const float* g1_bhh  = (const float*)d_in[12];
  const float* lin_W   = (const float*)d_in[13];
  const float* lin_b   = (const float*)d_in[14];
  const float* lin2_W  = (const float*)d_in[15];
  const float* lin2_b  = (const float*)d_in[16];
  const float* c_Wih   = (const float*)d_in[17];
  const float* c_Whh   = (const float*)d_in[18];
  const float* c_bih   = (const float*)d_in[19];
  const float* c_bhh   = (const float*)d_in[20];
  const float* hyp_W   = (const float*)d_in[21];
  const float* hyp_b   = (const float*)d_in[22];
  const float* bn_g    = (const float*)d_in[23];
  const float* bn_be   = (const float*)d_in[24];
  const float* bn_m    = (const float*)d_in[25];
  const float* bn_v    = (const float*)d_in[26];
  const float* out_W   = (const float*)d_in[27];
  const float* out_b   = (const float*)d_in[28];

  const size_t P = NPAIR;
  u16* hmsg  = (u16*)d_ws;
  u16* hself = hmsg  + P * 128;
  u16* wbase = hself + P * 128;
  float* bloss = (float*)(wbase + 409600);

  float* out = (float*)d_out;

  k_prep_all<<<dim3(192, 11), 256, 0, stream>>>(msg_W, lin_W, g0_Wih, g1_Wih,
      c_Wih, lin2_W, g0_Whh, g1_Whh, c_Whh, hyp_W, wbase);

  k1_fused<<<N_, 256, 0, stream>>>(X, C, wbase, wbase + 32768,
      msg_b, lin_b, hmsg, hself);

  k_chain<<<N_ / 16, 256, 0, stream>>>(hmsg, hself, wbase,
      g0_bih, g0_bhh, g1_bih, g1_bhh, lin2_b, c_bih, c_bhh,
      hyp_b, bn_g, bn_be, bn_m, bn_v, out_W, out_b, Y, out, bloss);

  k3_loss<<<1, 256, 0, stream>>>(bloss, out);
}

// Round 7
// 232.896 us; speedup vs baseline: 1.1553x; 1.1553x over previous
//
#include <hip/hip_runtime.h>
#include <math.h>

#define N_    4096
#define NPAIR (N_ * 7)   // 28672

typedef unsigned short u16;
typedef __attribute__((ext_vector_type(8))) short bf16x8;
typedef __attribute__((ext_vector_type(4))) float f32x4;

__device__ __forceinline__ float sigm(float x) { return 1.0f / (1.0f + __expf(-x)); }
__device__ __forceinline__ float tanh_fast(float x) { return 2.0f / (1.0f + __expf(-2.0f * x)) - 1.0f; }
__device__ __forceinline__ float bf2f(u16 u) { return __uint_as_float(((unsigned)u) << 16); }
__device__ __forceinline__ u16 f2bf(float f) {
  unsigned u = __float_as_uint(f);
  return (u16)((u + 0x7FFFu + ((u >> 16) & 1u)) >> 16);
}
__device__ __forceinline__ f32x4 mfma16(bf16x8 a, bf16x8 b, f32x4 c) {
  return __builtin_amdgcn_mfma_f32_16x16x32_bf16(a, b, c, 0, 0, 0);
}

// ---------------- k_prep_all: all weight fp32->bf16 conversions, one launch --------
__global__ __launch_bounds__(256) void k_prep_all(
    const float* __restrict__ msg_W, const float* __restrict__ lin_W,
    const float* __restrict__ g0_Wih, const float* __restrict__ g1_Wih,
    const float* __restrict__ c_Wih, const float* __restrict__ lin2_W,
    const float* __restrict__ g0_Whh, const float* __restrict__ g1_Whh,
    const float* __restrict__ c_Whh, const float* __restrict__ hyp_W,
    u16* __restrict__ wbase)
{
  const int task = blockIdx.y;
  const int i = blockIdx.x * 256 + threadIdx.x;
  int R, KD, stride, koff, doff;
  const float* src;
  switch (task) {
    case 0:  R=128; KD=256; stride=256; koff=0;   src=msg_W;  doff=0;      break;
    case 1:  R=128; KD=256; stride=256; koff=0;   src=lin_W;  doff=32768;  break;
    case 2:  R=384; KD=128; stride=128; koff=0;   src=g0_Wih; doff=65536;  break;
    case 3:  R=384; KD=128; stride=128; koff=0;   src=g1_Wih; doff=114688; break;
    case 4:  R=384; KD=128; stride=128; koff=0;   src=c_Wih;  doff=163840; break;
    case 5:  R=128; KD=128; stride=256; koff=128; src=lin2_W; doff=212992; break;  // l2w = lin2_W[:,128:]
    case 6:  R=128; KD=128; stride=256; koff=0;   src=lin2_W; doff=229376; break;  // w2a = lin2_W[:,:128]
    case 7:  R=384; KD=128; stride=128; koff=0;   src=g0_Whh; doff=245760; break;
    case 8:  R=384; KD=128; stride=128; koff=0;   src=g1_Whh; doff=294912; break;
    case 9:  R=384; KD=128; stride=128; koff=0;   src=c_Whh;  doff=344064; break;
    default: R=128; KD=128; stride=128; koff=0;   src=hyp_W;  doff=393216; break;
  }
  if (i >= R * KD) return;
  const int r = i / KD, k = i - r * KD;
  wbase[doff + i] = f2bf(src[(size_t)r * stride + koff + k]);
}

// ---------------- k1_fused: stream X + weighted reduce + msg/lin MFMA GEMM ----------
// R5 structure (16 pairs/block, 8 blocks/CU) + s_c LDS staging + nontemporal loads.
__global__ __launch_bounds__(256) void k1_fused(
    const float* __restrict__ X, const float* __restrict__ C,
    const u16* __restrict__ msgw, const u16* __restrict__ linw,   // [128][256] bf16
    const float* __restrict__ msg_b, const float* __restrict__ lin_b,
    u16* __restrict__ hmsg, u16* __restrict__ hself)
{
  __shared__ u16 sXW[16 * 256];
  __shared__ u16 sTX[16 * 256];
  __shared__ float s_c[4][224];
  __shared__ float s_ps[16];
  const int tid = threadIdx.x, wave = tid >> 6, lane = tid & 63;
  const int p0 = blockIdx.x * 16;
  const int nfirst = p0 / 7;

  // stage C for the (up to) 4 n-slabs this block touches
  for (int i = tid; i < 896; i += 256) {
    const int nn = nfirst + i / 224;
    s_c[i / 224][i % 224] = (nn < N_) ? C[(size_t)nn * 231 + 7 + (i % 224)] : 0.f;
  }
  __syncthreads();

  for (int q = 0; q < 4; ++q) {
    const int lp = wave * 4 + q;
    const int p = p0 + lp;
    const int n = p / 7, w = p - n * 7;
    const float* cr = &s_c[n - nfirst][0];
    const f32x4* xb = (const f32x4*)(X + ((size_t)(n * 33 + 1) * 7 + w) * 256) + lane;
    f32x4 acc = {0.f, 0.f, 0.f, 0.f};
    float ps = 0.f;
    #pragma unroll 8
    for (int m = 0; m < 32; ++m) {
      const float c = cr[m * 7 + w];
      const f32x4 x4 = __builtin_nontemporal_load(xb + (size_t)m * 448);
      acc += x4 * c;
      ps += c;
    }
    const int sb = lp * 512 + ((lane * 8) ^ ((lp & 7) << 4));
    ushort4 o = {f2bf(acc[0]), f2bf(acc[1]), f2bf(acc[2]), f2bf(acc[3])};
    *(ushort4*)((char*)sXW + sb) = o;
    const f32x4 t4 = __builtin_nontemporal_load(
        (const f32x4*)(X + ((size_t)n * 231 + w) * 256) + lane);
    ushort4 ot = {f2bf(t4[0]), f2bf(t4[1]), f2bf(t4[2]), f2bf(t4[3])};
    *(ushort4*)((char*)sTX + sb) = ot;
    if (lane == 0) s_ps[lp] = ps;
  }
  __syncthreads();

  const int l15 = lane & 15, lq = lane >> 4;
  bf16x8 ax[8], at[8];
  #pragma unroll
  for (int kc = 0; kc < 8; ++kc) {
    const int off = l15 * 512 + ((lq * 16 + kc * 64) ^ ((l15 & 7) << 4));
    ax[kc] = *(const bf16x8*)((const char*)sXW + off);
    at[kc] = *(const bf16x8*)((const char*)sTX + off);
  }
  float psr[4];
  #pragma unroll
  for (int r = 0; r < 4; ++r) psr[r] = s_ps[lq * 4 + r];

  #pragma unroll
  for (int ct = 0; ct < 2; ++ct) {
    const int col = (wave + ct * 4) * 16 + l15;
    f32x4 am = {0.f, 0.f, 0.f, 0.f}, as = {0.f, 0.f, 0.f, 0.f};
    #pragma unroll
    for (int kc = 0; kc < 8; ++kc) {
      const bf16x8 bm = *(const bf16x8*)(msgw + (size_t)col * 256 + lq * 8 + kc * 32);
      const bf16x8 bl = *(const bf16x8*)(linw + (size_t)col * 256 + lq * 8 + kc * 32);
      am = mfma16(ax[kc], bm, am);
      as = mfma16(at[kc], bl, as);
    }
    const float mb = msg_b[col], lb = lin_b[col];
    #pragma unroll
    for (int r = 0; r < 4; ++r) {
      const int p = p0 + lq * 4 + r;
      hmsg[(size_t)p * 128 + col]  = f2bf(am[r] + mb * psr[r]);
      hself[(size_t)p * 128 + col] = f2bf(as[r] + lb);
    }
  }
}

// ---------------- k_chain: 8-wave version (wave owns one 16-wide d-tile) ------------
__device__ __forceinline__ void stage16(u16* __restrict__ dst,
                                        const u16* __restrict__ src,
                                        int n0, int tid)
{
  for (int i = tid; i < 1792; i += 512) {
    const int w = i >> 8, rem = i & 255;
    const int n = rem >> 4, d0 = (rem & 15) * 8;
    const uint4 v = *(const uint4*)(src + ((size_t)(n0 + n) * 7 + w) * 128 + d0);
    *(uint4*)((char*)dst + w * 4096 + n * 256 + ((d0 * 2) ^ ((n & 7) << 4))) = v;
  }
}

__device__ __forceinline__ void gru_stage8(
    const u16* __restrict__ sin, u16* __restrict__ sout,
    const u16* __restrict__ wih, const u16* __restrict__ whh,
    const float* __restrict__ bih, const float* __restrict__ bhh,
    int d, int l15, int lq)
{
  bf16x8 wiR[4], wiZ[4], wiN[4], whR[4], whZ[4], whN[4];
  #pragma unroll
  for (int kc = 0; kc < 4; ++kc) {
    wiR[kc] = *(const bf16x8*)(wih + (size_t)d * 128 + lq * 8 + kc * 32);
    wiZ[kc] = *(const bf16x8*)(wih + (size_t)(d + 128) * 128 + lq * 8 + kc * 32);
    wiN[kc] = *(const bf16x8*)(wih + (size_t)(d + 256) * 128 + lq * 8 + kc * 32);
    whR[kc] = *(const bf16x8*)(whh + (size_t)d * 128 + lq * 8 + kc * 32);
    whZ[kc] = *(const bf16x8*)(whh + (size_t)(d + 128) * 128 + lq * 8 + kc * 32);
    whN[kc] = *(const bf16x8*)(whh + (size_t)(d + 256) * 128 + lq * 8 + kc * 32);
  }
  const float bR = bih[d] + bhh[d];
  const float bZ = bih[d + 128] + bhh[d + 128];
  const float bNh = bhh[d + 256], bNx = bih[d + 256];
  float hold[4] = {0.f, 0.f, 0.f, 0.f};

  for (int w = 0; w < 7; ++w) {
    bf16x8 afx[4], afh[4];
    #pragma unroll
    for (int kc = 0; kc < 4; ++kc) {
      const int off = l15 * 256 + ((lq * 16 + kc * 64) ^ ((l15 & 7) << 4));
      afx[kc] = *(const bf16x8*)((const char*)sin + w * 4096 + off);
      if (w) afh[kc] = *(const bf16x8*)((const char*)sout + (w - 1) * 4096 + off);
    }
    f32x4 aR = {bR, bR, bR, bR}, aZ = {bZ, bZ, bZ, bZ};
    f32x4 aNh = {bNh, bNh, bNh, bNh}, aNx = {bNx, bNx, bNx, bNx};
    #pragma unroll
    for (int kc = 0; kc < 4; ++kc) {
      aR  = mfma16(afx[kc], wiR[kc], aR);
      aZ  = mfma16(afx[kc], wiZ[kc], aZ);
      aNx = mfma16(afx[kc], wiN[kc], aNx);
      if (w) {
        aR  = mfma16(afh[kc], whR[kc], aR);
        aZ  = mfma16(afh[kc], whZ[kc], aZ);
        aNh = mfma16(afh[kc], whN[kc], aNh);
      }
    }
    #pragma unroll
    for (int r = 0; r < 4; ++r) {
      const float rg = sigm(aR[r]);
      const float zg = sigm(aZ[r]);
      const float nn = tanh_fast(aNx[r] + rg * aNh[r]);
      const float hv = (1.f - zg) * nn + zg * hold[r];
      hold[r] = hv;
      const int n = lq * 4 + r;
      *(u16*)((char*)sout + w * 4096 + n * 256 + ((d * 2) ^ ((n & 7) << 4))) = f2bf(hv);
    }
    __syncthreads();
  }
}

__global__ __launch_bounds__(512, 2) void k_chain(
    const u16* __restrict__ hmsg, const u16* __restrict__ hself,
    const u16* __restrict__ wbase,
    const float* __restrict__ g0_bih, const float* __restrict__ g0_bhh,
    const float* __restrict__ g1_bih, const float* __restrict__ g1_bhh,
    const float* __restrict__ lin2_b,
    const float* __restrict__ c_bih, const float* __restrict__ c_bhh,
    const float* __restrict__ hyp_b,
    const float* __restrict__ bn_g, const float* __restrict__ bn_be,
    const float* __restrict__ bn_m, const float* __restrict__ bn_v,
    const float* __restrict__ out_W, const float* __restrict__ out_b,
    const float* __restrict__ Y,
    float* __restrict__ outp, float* __restrict__ bloss)
{
  __shared__ u16 sA[7 * 2048];   // 28 KB
  __shared__ u16 sB[7 * 2048];   // 28 KB
  __shared__ u16 sC[2048];       // 4 KB
  __shared__ u16 sD[2048];       // 4 KB
  __shared__ float s_red[16][130];
  __shared__ float s_ls[16];

  const int tid = threadIdx.x;
  const int lane = tid & 63, wave = tid >> 6;     // wave 0..7
  const int l15 = lane & 15, lq = lane >> 4;
  const int d = wave * 16 + l15;                  // this wave's d-tile
  const int n0 = blockIdx.x * 16;

  const u16* g0wih = wbase + 65536;
  const u16* g1wih = wbase + 114688;
  const u16* cwih  = wbase + 163840;
  const u16* l2w   = wbase + 212992;
  const u16* w2a   = wbase + 229376;
  const u16* whh0  = wbase + 245760;
  const u16* whh1  = wbase + 294912;
  const u16* whhc  = wbase + 344064;
  const u16* hypw  = wbase + 393216;

  stage16(sA, hmsg, n0, tid);
  __syncthreads();

  gru_stage8(sA, sB, g0wih, whh0, g0_bih, g0_bhh, d, l15, lq);  // h0 -> sB
  gru_stage8(sB, sA, g1wih, whh1, g1_bih, g1_bhh, d, l15, lq);  // h1 -> sA

  stage16(sB, hself, n0, tid);   // h0 dead; sB <- hself
  __syncthreads();

  // ---- cell chain: hx1 = tanh(w2a@hx + l2w@h1 + b2); hx = GRU_c(Wc@hself, hx1) ----
  {
    bf16x8 lw[4], wa[4], wiR[4], wiZ[4], wiN[4], whR[4], whZ[4], whN[4];
    #pragma unroll
    for (int kc = 0; kc < 4; ++kc) {
      lw[kc]  = *(const bf16x8*)(l2w + (size_t)d * 128 + lq * 8 + kc * 32);
      wa[kc]  = *(const bf16x8*)(w2a + (size_t)d * 128 + lq * 8 + kc * 32);
      wiR[kc] = *(const bf16x8*)(cwih + (size_t)d * 128 + lq * 8 + kc * 32);
      wiZ[kc] = *(const bf16x8*)(cwih + (size_t)(d + 128) * 128 + lq * 8 + kc * 32);
      wiN[kc] = *(const bf16x8*)(cwih + (size_t)(d + 256) * 128 + lq * 8 + kc * 32);
      whR[kc] = *(const bf16x8*)(whhc + (size_t)d * 128 + lq * 8 + kc * 32);
      whZ[kc] = *(const bf16x8*)(whhc + (size_t)(d + 128) * 128 + lq * 8 + kc * 32);
      whN[kc] = *(const bf16x8*)(whhc + (size_t)(d + 256) * 128 + lq * 8 + kc * 32);
    }
    const float b2 = lin2_b[d];
    const float bR = c_bih[d] + c_bhh[d];
    const float bZ = c_bih[d + 128] + c_bhh[d + 128];
    const float bNh = c_bhh[d + 256], bNx = c_bih[d + 256];

    for (int w = 0; w < 7; ++w) {
      // round 1: hx1 = tanh(w2a@hx_prev + l2w@h1_w + b2)
      bf16x8 af1[4], afx_[4];
      #pragma unroll
      for (int kc = 0; kc < 4; ++kc) {
        const int off = l15 * 256 + ((lq * 16 + kc * 64) ^ ((l15 & 7) << 4));
        af1[kc] = *(const bf16x8*)((const char*)sA + w * 4096 + off);
        if (w) afx_[kc] = *(const bf16x8*)((const char*)sD + off);
      }
      f32x4 a1 = {b2, b2, b2, b2};
      #pragma unroll
      for (int kc = 0; kc < 4; ++kc) {
        a1 = mfma16(af1[kc], lw[kc], a1);
        if (w) a1 = mfma16(afx_[kc], wa[kc], a1);
      }
      float hx1[4];
      #pragma unroll
      for (int r = 0; r < 4; ++r) {
        hx1[r] = tanh_fast(a1[r]);
        const int n = lq * 4 + r;
        *(u16*)((char*)sC + n * 256 + ((d * 2) ^ ((n & 7) << 4))) = f2bf(hx1[r]);
      }
      __syncthreads();

      // round 2: cell GRU (x-gates from hself, state = hx1)
      bf16x8 afs[4], aft[4];
      #pragma unroll
      for (int kc = 0; kc < 4; ++kc) {
        const int off = l15 * 256 + ((lq * 16 + kc * 64) ^ ((l15 & 7) << 4));
        afs[kc] = *(const bf16x8*)((const char*)sB + w * 4096 + off);
        aft[kc] = *(const bf16x8*)((const char*)sC + off);
      }
      f32x4 aR = {bR, bR, bR, bR}, aZ = {bZ, bZ, bZ, bZ};
      f32x4 aNh = {bNh, bNh, bNh, bNh}, aNx = {bNx, bNx, bNx, bNx};
      #pragma unroll
      for (int kc = 0; kc < 4; ++kc) {
        aR  = mfma16(afs[kc], wiR[kc], aR);
        aZ  = mfma16(afs[kc], wiZ[kc], aZ);
        aNx = mfma16(afs[kc], wiN[kc], aNx);
        aR  = mfma16(aft[kc], whR[kc], aR);
        aZ  = mfma16(aft[kc], whZ[kc], aZ);
        aNh = mfma16(aft[kc], whN[kc], aNh);
      }
      #pragma unroll
      for (int r = 0; r < 4; ++r) {
        const float rg = sigm(aR[r]);
        const float zg = sigm(aZ[r]);
        const float nn = tanh_fast(aNx[r] + rg * aNh[r]);
        const float hv = (1.f - zg) * nn + zg * hx1[r];
        const int n = lq * 4 + r;
        *(u16*)((char*)sD + n * 256 + ((d * 2) ^ ((n & 7) << 4))) = f2bf(hv);
      }
      __syncthreads();
    }
  }

  // ---- head: relu(BN(hyp_W@hx + hyp_b)) -> y -> sigmoid + loss partial ----
  {
    bf16x8 af[4];
    #pragma unroll
    for (int kc = 0; kc < 4; ++kc) {
      const int off = l15 * 256 + ((lq * 16 + kc * 64) ^ ((l15 & 7) << 4));
      af[kc] = *(const bf16x8*)((const char*)sD + off);
    }
    const float hb = hyp_b[d];
    f32x4 ah = {hb, hb, hb, hb};
    #pragma unroll
    for (int kc = 0; kc < 4; ++kc) {
      const bf16x8 hf = *(const bf16x8*)(hypw + (size_t)d * 128 + lq * 8 + kc * 32);
      ah = mfma16(af[kc], hf, ah);
    }
    const float sc = rsqrtf(bn_v[d] + 1e-5f) * bn_g[d];
    const float mu = bn_m[d], be = bn_be[d], ow = out_W[d];
    #pragma unroll
    for (int r = 0; r < 4; ++r) {
      const float v = (ah[r] - mu) * sc + be;
      s_red[lq * 4 + r][d] = ow * fmaxf(v, 0.f);
    }
  }
  __syncthreads();
  if (tid < 16) {
    const int n = tid;
    float y = out_b[0];
    #pragma unroll 8
    for (int c = 0; c < 128; ++c) y += s_red[n][c];
    outp[1 + n0 + n] = 1.f / (1.f + __expf(-y));
    const float tY = Y[(size_t)(n0 + n) * 33];
    s_ls[n] = fmaxf(y, 0.f) - y * tY + log1pf(__expf(-fabsf(y)));
  }
  __syncthreads();
  if (tid == 0) {
    float s = 0.f;
    #pragma unroll
    for (int j = 0; j < 16; ++j) s += s_ls[j];
    bloss[blockIdx.x] = s;
  }
}

// ---------------- K3: loss reduction (256 partials) ----------------
__global__ __launch_bounds__(256) void k3_loss(const float* __restrict__ bloss,
                                               float* __restrict__ out)
{
  __shared__ float s[256];
  s[threadIdx.x] = bloss[threadIdx.x];
  __syncthreads();
  for (int off = 128; off > 0; off >>= 1) {
    if (threadIdx.x < off) s[threadIdx.x] += s[threadIdx.x + off];
    __syncthreads();
  }
  if (threadIdx.x == 0) out[0] = s[0] * (1.0f / 4096.0f);
}

extern "C" void kernel_launch(void* const* d_in, const int* in_sizes, int n_in,
                              void* d_out, int out_size, void* d_ws, size_t ws_size,
                              hipStream_t stream) {
  const float* X       = (const float*)d_in[0];
  const float* Y       = (const float*)d_in[1];
  const float* C       = (const float*)d_in[2];
  const float* msg_W   = (const float*)d_in[3];
  const float* msg_b   = (const float*)d_in[4];
  const float* g0_Wih  = (const float*)d_in[5];
  const float* g0_Whh  = (const float*)d_in[6];
  const float* g0_bih  = (const float*)d_in[7];
  const float* g0_bhh  = (const float*)d_in[8];
  const float* g1_Wih  = (const float*)d_in[9];
  const float* g1_Whh  = (const float*)d_in[10];
  const float* g1_bih  = (const float*)d_in[11];
  const float* g1_bhh  = (const float*)d_in[12];
  const float* lin_W   = (const float*)d_in[13];
  const float* lin_b   = (const float*)d_in[14];
  const float* lin2_W  = (const float*)d_in[15];
  const float* lin2_b  = (const float*)d_in[16];
  const float* c_Wih   = (const float*)d_in[17];
  const float* c_Whh   = (const float*)d_in[18];
  const float* c_bih   = (const float*)d_in[19];
  const float* c_bhh   = (const float*)d_in[20];
  const float* hyp_W   = (const float*)d_in[21];
  const float* hyp_b   = (const float*)d_in[22];
  const float* bn_g    = (const float*)d_in[23];
  const float* bn_be   = (const float*)d_in[24];
  const float* bn_m    = (const float*)d_in[25];
  const float* bn_v    = (const float*)d_in[26];
  const float* out_W   = (const float*)d_in[27];
  const float* out_b   = (const float*)d_in[28];

  const size_t P = NPAIR;
  u16* hmsg  = (u16*)d_ws;
  u16* hself = hmsg  + P * 128;
  u16* wbase = hself + P * 128;
  float* bloss = (float*)(wbase + 409600);

  float* out = (float*)d_out;

  k_prep_all<<<dim3(192, 11), 256, 0, stream>>>(msg_W, lin_W, g0_Wih, g1_Wih,
      c_Wih, lin2_W, g0_Whh, g1_Whh, c_Whh, hyp_W, wbase);

  k1_fused<<<NPAIR / 16, 256, 0, stream>>>(X, C, wbase, wbase + 32768,
      msg_b, lin_b, hmsg, hself);

  k_chain<<<N_ / 16, 512, 0, stream>>>(hmsg, hself, wbase,
      g0_bih, g0_bhh, g1_bih, g1_bhh, lin2_b, c_bih, c_bhh,
      hyp_b, bn_g, bn_be, bn_m, bn_v, out_W, out_b, Y, out, bloss);

  k3_loss<<<1, 256, 0, stream>>>(bloss, out);
}